// Round 1
// baseline (330.789 us; speedup 1.0000x reference)
//
#include <hip/hip_runtime.h>

typedef __attribute__((ext_vector_type(8))) short short8v;
typedef __attribute__((ext_vector_type(4))) float f32x4;

#define NN 40000
#define FF 512
#define HH 256
#define EE 320000
#define NHEADS 8
#define NEG_SLOPE 0.01f

__device__ __forceinline__ short f2bf(float x) {
    unsigned u = __float_as_uint(x);
    u += 0x7fffu + ((u >> 16) & 1u);
    return (short)(u >> 16);
}

// ---------------- zero ----------------
__global__ void zero_kernel(int* __restrict__ p, int count) {
    int i = blockIdx.x * blockDim.x + threadIdx.x;
    if (i < count) p[i] = 0;
}

// ---------------- feats f32 -> bf16 ----------------
__global__ void cvt_kernel(const float* __restrict__ in, short* __restrict__ out, int n4) {
    int i = blockIdx.x * blockDim.x + threadIdx.x;
    if (i < n4) {
        float4 v = reinterpret_cast<const float4*>(in)[i];
        short4 o;
        o.x = f2bf(v.x); o.y = f2bf(v.y); o.z = f2bf(v.z); o.w = f2bf(v.w);
        reinterpret_cast<short4*>(out)[i] = o;
    }
}

// ---------------- W (512x256) -> Wt bf16 (256x512) ----------------
__global__ void wt_kernel(const float* __restrict__ W, short* __restrict__ Wt) {
    int i = blockIdx.x * 256 + threadIdx.x;   // i < 512*256
    int k = i >> 8, n = i & 255;
    Wt[n * 512 + k] = f2bf(W[i]);
}

// ---------------- GEMM h = feats @ W + b  (bf16 MFMA, f32 out) ----------------
__global__ __launch_bounds__(256) void gemm_kernel(
    const short* __restrict__ Abf,   // 40000 x 512 bf16
    const short* __restrict__ Btf,   // 256 x 512 bf16 (n-major)
    const float* __restrict__ bias,  // 256
    float* __restrict__ hout)        // 40000 x 256 f32
{
    __shared__ short8v ldsA[1024];   // [row 0..127][slot 0..7], 16B units, XOR-swizzled
    __shared__ short8v ldsB[1024];
    const int tid = threadIdx.x;
    const int lane = tid & 63, w = tid >> 6;
    const int wm = w >> 1, wn = w & 1;
    const int r0 = blockIdx.x * 128;
    const int n0 = blockIdx.y * 128;

    short8v regA[4], regB[4];

    auto stage_load = [&](const short* __restrict__ src, int rowbase, int rowmax, int k0, short8v* regs) {
        #pragma unroll
        for (int c = 0; c < 4; ++c) {
            int u = tid + c * 256;
            int row = u >> 3, slot = u & 7;
            int gr = rowbase + row; if (gr > rowmax) gr = rowmax;
            regs[c] = *reinterpret_cast<const short8v*>(src + (size_t)gr * 512 + k0 + slot * 8);
        }
    };
    auto stage_store = [&](short8v* ldsT, short8v* regs) {
        #pragma unroll
        for (int c = 0; c < 4; ++c) {
            int u = tid + c * 256;
            int row = u >> 3, slot = u & 7;
            ldsT[row * 8 + (slot ^ (row & 7))] = regs[c];
        }
    };

    f32x4 acc[4][4];
    #pragma unroll
    for (int i = 0; i < 4; ++i)
        #pragma unroll
        for (int j = 0; j < 4; ++j)
            acc[i][j] = {0.f, 0.f, 0.f, 0.f};

    stage_load(Abf, r0, NN - 1, 0, regA);
    stage_load(Btf, n0, 255, 0, regB);

    for (int kt = 0; kt < 8; ++kt) {
        __syncthreads();
        stage_store(ldsA, regA);
        stage_store(ldsB, regB);
        __syncthreads();
        if (kt < 7) {
            stage_load(Abf, r0, NN - 1, (kt + 1) * 64, regA);
            stage_load(Btf, n0, 255, (kt + 1) * 64, regB);
        }
        #pragma unroll
        for (int kc = 0; kc < 2; ++kc) {
            short8v af[4], bfr[4];
            int kslot = kc * 4 + (lane >> 4);
            #pragma unroll
            for (int mr = 0; mr < 4; ++mr) {
                int row = wm * 64 + mr * 16 + (lane & 15);
                af[mr] = ldsA[row * 8 + (kslot ^ (row & 7))];
            }
            #pragma unroll
            for (int nr = 0; nr < 4; ++nr) {
                int col = wn * 64 + nr * 16 + (lane & 15);
                bfr[nr] = ldsB[col * 8 + (kslot ^ (col & 7))];
            }
            #pragma unroll
            for (int mr = 0; mr < 4; ++mr)
                #pragma unroll
                for (int nr = 0; nr < 4; ++nr)
                    acc[mr][nr] = __builtin_amdgcn_mfma_f32_16x16x32_bf16(
                        af[mr], bfr[nr], acc[mr][nr], 0, 0, 0);
        }
    }

    #pragma unroll
    for (int mr = 0; mr < 4; ++mr) {
        #pragma unroll
        for (int nr = 0; nr < 4; ++nr) {
            int gc = n0 + wn * 64 + nr * 16 + (lane & 15);
            float b = bias[gc];
            #pragma unroll
            for (int j = 0; j < 4; ++j) {
                int gr = r0 + wm * 64 + mr * 16 + (lane >> 4) * 4 + j;
                if (gr < NN) hout[(size_t)gr * 256 + gc] = acc[mr][nr][j] + b;
            }
        }
    }
}

// ---------------- per-node attention projections ----------------
__global__ __launch_bounds__(256) void sproj_kernel(
    const float* __restrict__ h, const float* __restrict__ attn_w,
    float* __restrict__ s_src, float* __restrict__ s_dst)
{
    int wid = threadIdx.x >> 6, lane = threadIdx.x & 63;
    int n = blockIdx.x * 4 + wid;
    if (n >= NN) return;
    float4 hv = *reinterpret_cast<const float4*>(h + (size_t)n * 256 + lane * 4);
    float ss[8], sd[8];
    #pragma unroll
    for (int q = 0; q < 8; ++q) {
        float4 as = *reinterpret_cast<const float4*>(attn_w + q * 512 + lane * 4);
        float4 ad = *reinterpret_cast<const float4*>(attn_w + q * 512 + 256 + lane * 4);
        ss[q] = hv.x * as.x + hv.y * as.y + hv.z * as.z + hv.w * as.w;
        sd[q] = hv.x * ad.x + hv.y * ad.y + hv.z * ad.z + hv.w * ad.w;
    }
    #pragma unroll
    for (int q = 0; q < 8; ++q) {
        #pragma unroll
        for (int off = 32; off >= 1; off >>= 1) {
            ss[q] += __shfl_xor(ss[q], off);
            sd[q] += __shfl_xor(sd[q], off);
        }
    }
    if (lane == 0) {
        #pragma unroll
        for (int q = 0; q < 8; ++q) {
            s_src[(size_t)n * 8 + q] = ss[q];
            s_dst[(size_t)n * 8 + q] = sd[q];
        }
    }
}

// ---------------- per-edge scores + degree count ----------------
__global__ void edge_kernel(const int* __restrict__ src, const int* __restrict__ dst,
                            const float* __restrict__ s_src, const float* __restrict__ s_dst,
                            const float* __restrict__ attn_b,
                            float* __restrict__ scores, int* __restrict__ deg)
{
    int e = blockIdx.x * 256 + threadIdx.x;
    if (e >= EE) return;
    int s = src[e], d = dst[e];
    float4 a0 = reinterpret_cast<const float4*>(s_src + (size_t)s * 8)[0];
    float4 a1 = reinterpret_cast<const float4*>(s_src + (size_t)s * 8)[1];
    float4 c0 = reinterpret_cast<const float4*>(s_dst + (size_t)d * 8)[0];
    float4 c1 = reinterpret_cast<const float4*>(s_dst + (size_t)d * 8)[1];
    float4 b0 = reinterpret_cast<const float4*>(attn_b)[0];
    float4 b1 = reinterpret_cast<const float4*>(attn_b)[1];
    float v[8];
    v[0] = a0.x + c0.x + b0.x; v[1] = a0.y + c0.y + b0.y;
    v[2] = a0.z + c0.z + b0.z; v[3] = a0.w + c0.w + b0.w;
    v[4] = a1.x + c1.x + b1.x; v[5] = a1.y + c1.y + b1.y;
    v[6] = a1.z + c1.z + b1.z; v[7] = a1.w + c1.w + b1.w;
    #pragma unroll
    for (int q = 0; q < 8; ++q) v[q] = v[q] > 0.f ? v[q] : NEG_SLOPE * v[q];
    float4 o0 = {v[0], v[1], v[2], v[3]};
    float4 o1 = {v[4], v[5], v[6], v[7]};
    reinterpret_cast<float4*>(scores + (size_t)e * 8)[0] = o0;
    reinterpret_cast<float4*>(scores + (size_t)e * 8)[1] = o1;
    atomicAdd(&deg[s], 1);
}

// ---------------- exclusive scan of degrees (single block) ----------------
__global__ __launch_bounds__(1024) void scan_kernel(const int* __restrict__ deg,
                                                    int* __restrict__ rowstart)
{
    __shared__ int buf[1024];
    __shared__ int carry;
    int tid = threadIdx.x;
    if (tid == 0) carry = 0;
    __syncthreads();
    for (int base = 0; base < NN; base += 1024) {
        int i = base + tid;
        int v = (i < NN) ? deg[i] : 0;
        buf[tid] = v;
        __syncthreads();
        #pragma unroll
        for (int off = 1; off < 1024; off <<= 1) {
            int t = (tid >= off) ? buf[tid - off] : 0;
            __syncthreads();
            buf[tid] += t;
            __syncthreads();
        }
        int inc = buf[tid];
        int c = carry;
        if (i < NN) rowstart[i] = c + inc - v;
        __syncthreads();
        if (tid == 1023) carry = c + inc;
        __syncthreads();
    }
    if (tid == 0) rowstart[NN] = carry;
}

// ---------------- CSR fill ----------------
__global__ void fill_kernel(const int* __restrict__ src, const int* __restrict__ rowstart,
                            int* __restrict__ cursor, int* __restrict__ csr)
{
    int e = blockIdx.x * 256 + threadIdx.x;
    if (e >= EE) return;
    int s = src[e];
    int pos = atomicAdd(&cursor[s], 1);
    csr[rowstart[s] + pos] = e;
}

// ---------------- per-node softmax + aggregation (wave per node) ----------------
__global__ __launch_bounds__(256) void agg_kernel(
    const float* __restrict__ h, const float* __restrict__ scores,
    const int* __restrict__ csr, const int* __restrict__ rowstart,
    const int* __restrict__ dstArr, float* __restrict__ out)
{
    int wid = threadIdx.x >> 6, lane = threadIdx.x & 63;
    int n = blockIdx.x * 4 + wid;
    if (n >= NN) return;
    int start = rowstart[n];
    int deg = rowstart[n + 1] - start;
    int ei = lane >> 3, hh = lane & 7;

    const float NEGBIG = -3.0e38f;
    float m = NEGBIG;
    float sc0 = NEGBIG; int e0 = 0;
    for (int base = 0; base < deg; base += 8) {
        int idx = base + ei;
        float sc = NEGBIG; int e = 0;
        if (idx < deg) { e = csr[start + idx]; sc = scores[(size_t)e * 8 + hh]; }
        if (base == 0) { sc0 = sc; e0 = e; }
        m = fmaxf(m, sc);
    }
    m = fmaxf(m, __shfl_xor(m, 8));
    m = fmaxf(m, __shfl_xor(m, 16));
    m = fmaxf(m, __shfl_xor(m, 32));

    float den = 0.f;
    for (int base = 0; base < deg; base += 8) {
        int idx = base + ei;
        float sc = (base == 0) ? sc0
                 : ((idx < deg) ? scores[(size_t)csr[start + idx] * 8 + hh] : 0.f);
        if (idx < deg) den += __expf(sc - m);
    }
    den += __shfl_xor(den, 8);
    den += __shfl_xor(den, 16);
    den += __shfl_xor(den, 32);
    float rden = (deg > 0) ? 1.f / den : 0.f;

    float4 hv = *reinterpret_cast<const float4*>(h + (size_t)n * 256 + lane * 4);
    float4 acc[8];
    #pragma unroll
    for (int q = 0; q < 8; ++q) acc[q] = hv;

    for (int base = 0; base < deg; base += 8) {
        int idx = base + ei;
        int e; float sc;
        if (base == 0) { e = e0; sc = sc0; }
        else if (idx < deg) { e = csr[start + idx]; sc = scores[(size_t)e * 8 + hh]; }
        else { e = 0; sc = 0.f; }
        float alpha = (idx < deg) ? __expf(sc - m) * rden : 0.f;
        int cnt = min(8, deg - base);
        for (int t = 0; t < cnt; ++t) {
            int ee = __shfl(e, t * 8);
            int dd = dstArr[ee];
            float4 hd = *reinterpret_cast<const float4*>(h + (size_t)dd * 256 + lane * 4);
            #pragma unroll
            for (int q = 0; q < 8; ++q) {
                float ah = __shfl(alpha, t * 8 + q);
                acc[q].x += ah * hd.x; acc[q].y += ah * hd.y;
                acc[q].z += ah * hd.z; acc[q].w += ah * hd.w;
            }
        }
    }

    float* orow = out + (size_t)n * 2048;
    #pragma unroll
    for (int q = 0; q < 8; ++q)
        *reinterpret_cast<float4*>(orow + q * 256 + lane * 4) = acc[q];
}

extern "C" void kernel_launch(void* const* d_in, const int* in_sizes, int n_in,
                              void* d_out, int out_size, void* d_ws, size_t ws_size,
                              hipStream_t stream) {
    const float* feats  = (const float*)d_in[0];
    const int*   adj    = (const int*)d_in[2];
    const float* W_w    = (const float*)d_in[3];
    const float* W_b    = (const float*)d_in[4];
    const float* attn_w = (const float*)d_in[5];
    const float* attn_b = (const float*)d_in[6];
    float* out = (float*)d_out;
    const int* srcA = adj;
    const int* dstA = adj + EE;

    char* ws = (char*)d_ws;
    size_t off = 0;
    auto alloc = [&](size_t bytes) -> void* {
        void* p = ws + off;
        off += (bytes + 255) & ~(size_t)255;
        return p;
    };
    short* featsbf = (short*)alloc((size_t)NN * FF * 2);
    short* Wt      = (short*)alloc((size_t)HH * FF * 2);
    float* h       = (float*)alloc((size_t)NN * HH * 4);
    float* s_src   = (float*)alloc((size_t)NN * 8 * 4);
    float* s_dst   = (float*)alloc((size_t)NN * 8 * 4);
    float* scores  = (float*)alloc((size_t)EE * 8 * 4);
    int*   deg     = (int*)alloc((size_t)NN * 4 * 2);  // deg + cursor contiguous
    int*   cursor  = deg + NN;
    int*   rowstart= (int*)alloc((size_t)(NN + 1) * 4);
    int*   csr     = (int*)alloc((size_t)EE * 4);

    zero_kernel<<<(2 * NN + 255) / 256, 256, 0, stream>>>(deg, 2 * NN);
    cvt_kernel<<<(NN * FF / 4 + 255) / 256, 256, 0, stream>>>(feats, featsbf, NN * FF / 4);
    wt_kernel<<<512, 256, 0, stream>>>(W_w, Wt);
    gemm_kernel<<<dim3((NN + 127) / 128, 2), 256, 0, stream>>>(featsbf, Wt, W_b, h);
    sproj_kernel<<<NN / 4, 256, 0, stream>>>(h, attn_w, s_src, s_dst);
    edge_kernel<<<(EE + 255) / 256, 256, 0, stream>>>(srcA, dstA, s_src, s_dst, attn_b, scores, deg);
    scan_kernel<<<1, 1024, 0, stream>>>(deg, rowstart);
    fill_kernel<<<(EE + 255) / 256, 256, 0, stream>>>(srcA, rowstart, cursor, csr);
    agg_kernel<<<NN / 4, 256, 0, stream>>>(h, scores, csr, rowstart, dstA, out);
}

// Round 2
// 248.466 us; speedup vs baseline: 1.3313x; 1.3313x over previous
//
#include <hip/hip_runtime.h>

typedef __attribute__((ext_vector_type(8))) short short8v;
typedef __attribute__((ext_vector_type(4))) float f32x4;

#define NN 40000
#define FF 512
#define HH 256
#define EE 320000
#define NHEADS 8
#define NEG_SLOPE 0.01f
#define NB 157   // ceil(NN/256)

__device__ __forceinline__ short f2bf(float x) {
    unsigned u = __float_as_uint(x);
    u += 0x7fffu + ((u >> 16) & 1u);
    return (short)(u >> 16);
}

// ---------------- zero ----------------
__global__ void zero_kernel(int* __restrict__ p, int count) {
    int i = blockIdx.x * blockDim.x + threadIdx.x;
    if (i < count) p[i] = 0;
}

// ---------------- W (512x256) -> Wt bf16 (256x512) ----------------
__global__ void wt_kernel(const float* __restrict__ W, short* __restrict__ Wt) {
    int i = blockIdx.x * 256 + threadIdx.x;   // i < 512*256
    int k = i >> 8, n = i & 255;
    Wt[n * 512 + k] = f2bf(W[i]);
}

// ---------------- GEMM h = feats @ W + b  (fused f32->bf16, BM=64 BN=256) ----------------
__global__ __launch_bounds__(512) void gemm_kernel(
    const float* __restrict__ feats, // 40000 x 512 f32
    const short* __restrict__ Btf,   // 256 x 512 bf16 (n-major)
    const float* __restrict__ bias,  // 256
    float* __restrict__ hout)        // 40000 x 256 f32
{
    __shared__ short8v ldsA[512];    // [row 0..63][slot 0..7], XOR-swizzled
    __shared__ short8v ldsB[2048];   // [col 0..255][slot 0..7]
    const int tid = threadIdx.x;
    const int lane = tid & 63, w = tid >> 6;
    const int wm = w >> 2, wn = w & 3;          // 2 x 4 wave grid
    const int r0 = blockIdx.x * 64;

    const int arow = tid >> 3, aslot = tid & 7; // A staging coords (1 unit/thread)

    float4 regA[2];
    short8v regB[4];

    auto stage_loadA = [&](int k0) {
        const float* p = feats + (size_t)(r0 + arow) * 512 + k0 + aslot * 8;
        regA[0] = *reinterpret_cast<const float4*>(p);
        regA[1] = *reinterpret_cast<const float4*>(p + 4);
    };
    auto stage_loadB = [&](int k0) {
        #pragma unroll
        for (int c = 0; c < 4; ++c) {
            int u = tid + c * 512;
            int row = u >> 3, slot = u & 7;
            regB[c] = *reinterpret_cast<const short8v*>(Btf + (size_t)row * 512 + k0 + slot * 8);
        }
    };
    auto stage_store = [&]() {
        short8v v;
        #pragma unroll
        for (int j = 0; j < 4; ++j) {
            v[j]     = f2bf(regA[0][j]);
            v[4 + j] = f2bf(regA[1][j]);
        }
        ldsA[arow * 8 + (aslot ^ (arow & 7))] = v;
        #pragma unroll
        for (int c = 0; c < 4; ++c) {
            int u = tid + c * 512;
            int row = u >> 3, slot = u & 7;
            ldsB[row * 8 + (slot ^ (row & 7))] = regB[c];
        }
    };

    f32x4 acc[2][4];
    #pragma unroll
    for (int i = 0; i < 2; ++i)
        #pragma unroll
        for (int j = 0; j < 4; ++j)
            acc[i][j] = {0.f, 0.f, 0.f, 0.f};

    stage_loadA(0);
    stage_loadB(0);

    for (int kt = 0; kt < 8; ++kt) {
        __syncthreads();
        stage_store();
        __syncthreads();
        if (kt < 7) {
            stage_loadA((kt + 1) * 64);
            stage_loadB((kt + 1) * 64);
        }
        #pragma unroll
        for (int kc = 0; kc < 2; ++kc) {
            short8v af[2], bfr[4];
            int kslot = kc * 4 + (lane >> 4);
            #pragma unroll
            for (int mr = 0; mr < 2; ++mr) {
                int row = wm * 32 + mr * 16 + (lane & 15);
                af[mr] = ldsA[row * 8 + (kslot ^ (row & 7))];
            }
            #pragma unroll
            for (int nr = 0; nr < 4; ++nr) {
                int col = wn * 64 + nr * 16 + (lane & 15);
                bfr[nr] = ldsB[col * 8 + (kslot ^ (col & 7))];
            }
            #pragma unroll
            for (int mr = 0; mr < 2; ++mr)
                #pragma unroll
                for (int nr = 0; nr < 4; ++nr)
                    acc[mr][nr] = __builtin_amdgcn_mfma_f32_16x16x32_bf16(
                        af[mr], bfr[nr], acc[mr][nr], 0, 0, 0);
        }
    }

    #pragma unroll
    for (int mr = 0; mr < 2; ++mr) {
        #pragma unroll
        for (int nr = 0; nr < 4; ++nr) {
            int gc = wn * 64 + nr * 16 + (lane & 15);
            float b = bias[gc];
            #pragma unroll
            for (int j = 0; j < 4; ++j) {
                int gr = r0 + wm * 32 + mr * 16 + (lane >> 4) * 4 + j;
                hout[(size_t)gr * 256 + gc] = acc[mr][nr][j] + b;
            }
        }
    }
}

// ---------------- per-node attention projections ----------------
__global__ __launch_bounds__(256) void sproj_kernel(
    const float* __restrict__ h, const float* __restrict__ attn_w,
    float* __restrict__ s_src, float* __restrict__ s_dst)
{
    int wid = threadIdx.x >> 6, lane = threadIdx.x & 63;
    int n = blockIdx.x * 4 + wid;
    if (n >= NN) return;
    float4 hv = *reinterpret_cast<const float4*>(h + (size_t)n * 256 + lane * 4);
    float ss[8], sd[8];
    #pragma unroll
    for (int q = 0; q < 8; ++q) {
        float4 as = *reinterpret_cast<const float4*>(attn_w + q * 512 + lane * 4);
        float4 ad = *reinterpret_cast<const float4*>(attn_w + q * 512 + 256 + lane * 4);
        ss[q] = hv.x * as.x + hv.y * as.y + hv.z * as.z + hv.w * as.w;
        sd[q] = hv.x * ad.x + hv.y * ad.y + hv.z * ad.z + hv.w * ad.w;
    }
    #pragma unroll
    for (int q = 0; q < 8; ++q) {
        #pragma unroll
        for (int off = 32; off >= 1; off >>= 1) {
            ss[q] += __shfl_xor(ss[q], off);
            sd[q] += __shfl_xor(sd[q], off);
        }
    }
    if (lane == 0) {
        #pragma unroll
        for (int q = 0; q < 8; ++q) {
            s_src[(size_t)n * 8 + q] = ss[q];
            s_dst[(size_t)n * 8 + q] = sd[q];
        }
    }
}

// ---------------- per-edge scores + degree count ----------------
__global__ void edge_kernel(const int* __restrict__ src, const int* __restrict__ dst,
                            const float* __restrict__ s_src, const float* __restrict__ s_dst,
                            const float* __restrict__ attn_b,
                            float* __restrict__ scores, int* __restrict__ deg)
{
    int e = blockIdx.x * 256 + threadIdx.x;
    if (e >= EE) return;
    int s = src[e], d = dst[e];
    float4 a0 = reinterpret_cast<const float4*>(s_src + (size_t)s * 8)[0];
    float4 a1 = reinterpret_cast<const float4*>(s_src + (size_t)s * 8)[1];
    float4 c0 = reinterpret_cast<const float4*>(s_dst + (size_t)d * 8)[0];
    float4 c1 = reinterpret_cast<const float4*>(s_dst + (size_t)d * 8)[1];
    float4 b0 = reinterpret_cast<const float4*>(attn_b)[0];
    float4 b1 = reinterpret_cast<const float4*>(attn_b)[1];
    float v[8];
    v[0] = a0.x + c0.x + b0.x; v[1] = a0.y + c0.y + b0.y;
    v[2] = a0.z + c0.z + b0.z; v[3] = a0.w + c0.w + b0.w;
    v[4] = a1.x + c1.x + b1.x; v[5] = a1.y + c1.y + b1.y;
    v[6] = a1.z + c1.z + b1.z; v[7] = a1.w + c1.w + b1.w;
    #pragma unroll
    for (int q = 0; q < 8; ++q) v[q] = v[q] > 0.f ? v[q] : NEG_SLOPE * v[q];
    float4 o0 = {v[0], v[1], v[2], v[3]};
    float4 o1 = {v[4], v[5], v[6], v[7]};
    reinterpret_cast<float4*>(scores + (size_t)e * 8)[0] = o0;
    reinterpret_cast<float4*>(scores + (size_t)e * 8)[1] = o1;
    atomicAdd(&deg[s], 1);
}

// ---------------- hierarchical exclusive scan ----------------
__global__ __launch_bounds__(256) void scan1_kernel(const int* __restrict__ deg,
                                                    int* __restrict__ rowtmp,
                                                    int* __restrict__ partials)
{
    __shared__ int buf[256];
    int tid = threadIdx.x;
    int i = blockIdx.x * 256 + tid;
    int v = (i < NN) ? deg[i] : 0;
    buf[tid] = v;
    __syncthreads();
    #pragma unroll
    for (int off = 1; off < 256; off <<= 1) {
        int t = (tid >= off) ? buf[tid - off] : 0;
        __syncthreads();
        buf[tid] += t;
        __syncthreads();
    }
    if (i < NN) rowtmp[i] = buf[tid] - v;       // exclusive within block
    if (tid == 255) partials[blockIdx.x] = buf[255];
}

__global__ __launch_bounds__(256) void scan2_kernel(int* __restrict__ partials)
{
    __shared__ int buf[256];
    int tid = threadIdx.x;
    int v = (tid < NB) ? partials[tid] : 0;
    buf[tid] = v;
    __syncthreads();
    #pragma unroll
    for (int off = 1; off < 256; off <<= 1) {
        int t = (tid >= off) ? buf[tid - off] : 0;
        __syncthreads();
        buf[tid] += t;
        __syncthreads();
    }
    if (tid < NB) partials[tid] = buf[tid] - v;  // exclusive block offsets
}

__global__ __launch_bounds__(256) void scan3_kernel(const int* __restrict__ rowtmp,
                                                    const int* __restrict__ partials,
                                                    int* __restrict__ rowstart)
{
    int i = blockIdx.x * 256 + threadIdx.x;
    if (i < NN) rowstart[i] = rowtmp[i] + partials[i >> 8];
    if (i == 0) rowstart[NN] = EE;
}

// ---------------- CSR fill ----------------
__global__ void fill_kernel(const int* __restrict__ src, const int* __restrict__ rowstart,
                            int* __restrict__ cursor, int* __restrict__ csr)
{
    int e = blockIdx.x * 256 + threadIdx.x;
    if (e >= EE) return;
    int s = src[e];
    int pos = atomicAdd(&cursor[s], 1);
    csr[rowstart[s] + pos] = e;
}

// ---------------- per-node softmax + aggregation (wave per node) ----------------
__global__ __launch_bounds__(256) void agg_kernel(
    const float* __restrict__ h, const float* __restrict__ scores,
    const int* __restrict__ csr, const int* __restrict__ rowstart,
    const int* __restrict__ dstArr, float* __restrict__ out)
{
    int wid = threadIdx.x >> 6, lane = threadIdx.x & 63;
    int n = blockIdx.x * 4 + wid;
    if (n >= NN) return;
    int start = rowstart[n];
    int deg = rowstart[n + 1] - start;
    int ei = lane >> 3, hh = lane & 7;

    const float NEGBIG = -3.0e38f;
    float m = NEGBIG;
    float sc0 = NEGBIG; int e0 = 0;
    for (int base = 0; base < deg; base += 8) {
        int idx = base + ei;
        float sc = NEGBIG; int e = 0;
        if (idx < deg) { e = csr[start + idx]; sc = scores[(size_t)e * 8 + hh]; }
        if (base == 0) { sc0 = sc; e0 = e; }
        m = fmaxf(m, sc);
    }
    m = fmaxf(m, __shfl_xor(m, 8));
    m = fmaxf(m, __shfl_xor(m, 16));
    m = fmaxf(m, __shfl_xor(m, 32));

    float den = 0.f;
    for (int base = 0; base < deg; base += 8) {
        int idx = base + ei;
        float sc = (base == 0) ? sc0
                 : ((idx < deg) ? scores[(size_t)csr[start + idx] * 8 + hh] : 0.f);
        if (idx < deg) den += __expf(sc - m);
    }
    den += __shfl_xor(den, 8);
    den += __shfl_xor(den, 16);
    den += __shfl_xor(den, 32);
    float rden = (deg > 0) ? 1.f / den : 0.f;

    float4 hv = *reinterpret_cast<const float4*>(h + (size_t)n * 256 + lane * 4);
    float4 acc[8];
    #pragma unroll
    for (int q = 0; q < 8; ++q) acc[q] = hv;

    for (int base = 0; base < deg; base += 8) {
        int idx = base + ei;
        int e; float sc;
        if (base == 0) { e = e0; sc = sc0; }
        else if (idx < deg) { e = csr[start + idx]; sc = scores[(size_t)e * 8 + hh]; }
        else { e = 0; sc = 0.f; }
        float alpha = (idx < deg) ? __expf(sc - m) * rden : 0.f;
        int cnt = min(8, deg - base);
        for (int t = 0; t < cnt; ++t) {
            int ee = __shfl(e, t * 8);
            int dd = dstArr[ee];
            float4 hd = *reinterpret_cast<const float4*>(h + (size_t)dd * 256 + lane * 4);
            #pragma unroll
            for (int q = 0; q < 8; ++q) {
                float ah = __shfl(alpha, t * 8 + q);
                acc[q].x += ah * hd.x; acc[q].y += ah * hd.y;
                acc[q].z += ah * hd.z; acc[q].w += ah * hd.w;
            }
        }
    }

    float* orow = out + (size_t)n * 2048;
    #pragma unroll
    for (int q = 0; q < 8; ++q)
        *reinterpret_cast<float4*>(orow + q * 256 + lane * 4) = acc[q];
}

extern "C" void kernel_launch(void* const* d_in, const int* in_sizes, int n_in,
                              void* d_out, int out_size, void* d_ws, size_t ws_size,
                              hipStream_t stream) {
    const float* feats  = (const float*)d_in[0];
    const int*   adj    = (const int*)d_in[2];
    const float* W_w    = (const float*)d_in[3];
    const float* W_b    = (const float*)d_in[4];
    const float* attn_w = (const float*)d_in[5];
    const float* attn_b = (const float*)d_in[6];
    float* out = (float*)d_out;
    const int* srcA = adj;
    const int* dstA = adj + EE;

    char* ws = (char*)d_ws;
    size_t off = 0;
    auto alloc = [&](size_t bytes) -> void* {
        void* p = ws + off;
        off += (bytes + 255) & ~(size_t)255;
        return p;
    };
    short* Wt      = (short*)alloc((size_t)HH * FF * 2);
    float* h       = (float*)alloc((size_t)NN * HH * 4);
    float* s_src   = (float*)alloc((size_t)NN * 8 * 4);
    float* s_dst   = (float*)alloc((size_t)NN * 8 * 4);
    float* scores  = (float*)alloc((size_t)EE * 8 * 4);
    int*   deg     = (int*)alloc((size_t)NN * 4 * 2);  // deg + cursor contiguous
    int*   cursor  = deg + NN;
    int*   rowtmp  = (int*)alloc((size_t)NN * 4);
    int*   partials= (int*)alloc((size_t)256 * 4);
    int*   rowstart= (int*)alloc((size_t)(NN + 1) * 4);
    int*   csr     = (int*)alloc((size_t)EE * 4);

    zero_kernel<<<(2 * NN + 255) / 256, 256, 0, stream>>>(deg, 2 * NN);
    wt_kernel<<<512, 256, 0, stream>>>(W_w, Wt);
    gemm_kernel<<<NN / 64, 512, 0, stream>>>(feats, Wt, W_b, h);
    sproj_kernel<<<NN / 4, 256, 0, stream>>>(h, attn_w, s_src, s_dst);
    edge_kernel<<<(EE + 255) / 256, 256, 0, stream>>>(srcA, dstA, s_src, s_dst, attn_b, scores, deg);
    scan1_kernel<<<NB, 256, 0, stream>>>(deg, rowtmp, partials);
    scan2_kernel<<<1, 256, 0, stream>>>(partials);
    scan3_kernel<<<NB, 256, 0, stream>>>(rowtmp, partials, rowstart);
    fill_kernel<<<(EE + 255) / 256, 256, 0, stream>>>(srcA, rowstart, cursor, csr);
    agg_kernel<<<NN / 4, 256, 0, stream>>>(h, scores, csr, rowstart, dstA, out);
}